// Round 5
// baseline (105.983 us; speedup 1.0000x reference)
//
#include <hip/hip_runtime.h>
#include <cstddef>
#include <cstdint>

// SelfAttention2d: B=8, C=64, N=4096, IC=8
// R5: R4 math, restructured attn: KT=128 double-buffered Vs, 1 barrier/tile,
// compile-time NSPLIT; vectorized combine (8q x 8ch per thread).

#define Bb 8
#define Cc 64
#define NN 4096
#define IC 8
#define VSTR 136     // LDS V row stride (bf16 elems) for 128-key tiles
#define XSTR 72      // LDS Xs row stride in P2

typedef __attribute__((ext_vector_type(8)))  short bf16x8;
typedef __attribute__((ext_vector_type(16))) float f32x16;
typedef unsigned short ushort_t;
typedef unsigned int   uint_t;

#define LOG2E 1.4426950408889634f

static __device__ __forceinline__ uint_t f2bf(float x) {   // RNE
    union { float f; uint_t u; } v; v.f = x;
    uint_t r = v.u + 0x7FFF + ((v.u >> 16) & 1);
    return r >> 16;
}
static __device__ __forceinline__ float bitsf(uint_t u) {
    union { uint_t u; float f; } v; v.u = u; return v.f;
}
static __device__ __forceinline__ float fexp2(float x) {
#if __has_builtin(__builtin_amdgcn_exp2f)
    return __builtin_amdgcn_exp2f(x);
#else
    return exp2f(x);
#endif
}
static __device__ __forceinline__ uint_t fbits(float x) {
    union { float f; uint_t u; } v; v.f = x; return v.u;
}
// pack (lo=even, hi=odd) truncated bf16 pair via v_perm
static __device__ __forceinline__ uint_t packbf(float e, float o) {
#if __has_builtin(__builtin_amdgcn_perm)
    return __builtin_amdgcn_perm(fbits(o), fbits(e), 0x07060302u);
#else
    return (fbits(e) >> 16) | (fbits(o) & 0xFFFF0000u);
#endif
}

union U4B { uint4 u; bf16x8 v; };

// ---------------- P1: transpose x -> xbf [b][n][c] bf16; block 512: weights ----
__global__ __launch_bounds__(256) void p1_kernel(
    const float* __restrict__ x,
    const float* __restrict__ theta_w, const float* __restrict__ theta_b,
    const float* __restrict__ phi_w,   const float* __restrict__ phi_b,
    const float* __restrict__ g_w,     const float* __restrict__ g_b,
    ushort_t* __restrict__ xbf, ushort_t* __restrict__ Wbf, float* __restrict__ biasf)
{
    const int t = threadIdx.x;
    const int bid = blockIdx.x;
    if (bid < 512) {
        __shared__ float Xt[64 * 68];
        const int b  = bid >> 6;
        const int nt = (bid & 63) * 64;
        const int c = t >> 2, nsg = t & 3;
        const float* xs = x + ((size_t)(b * 64 + c)) * NN + nt + nsg * 16;
        #pragma unroll
        for (int i = 0; i < 4; i++) {
            float4 v = ((const float4*)xs)[i];
            *(float4*)(Xt + c * 68 + nsg * 16 + i * 4) = v;
        }
        __syncthreads();
        const int n = t & 63, cs = t >> 6;
        uint_t wv[8];
        #pragma unroll
        for (int i = 0; i < 8; i++) {
            float e0 = Xt[(cs * 16 + 2 * i + 0) * 68 + n];
            float e1 = Xt[(cs * 16 + 2 * i + 1) * 68 + n];
            wv[i] = f2bf(e0) | (f2bf(e1) << 16);
        }
        ushort_t* dst = xbf + ((size_t)(b * NN + nt + n)) * 64 + cs * 16;
        *(uint4*)dst       = make_uint4(wv[0], wv[1], wv[2], wv[3]);
        *(uint4*)(dst + 8) = make_uint4(wv[4], wv[5], wv[6], wv[7]);
    } else {
        // weights: Wbf[96][64] = [g(0-63); theta*log2e(64-71); phi(72-79); zero]
        for (int i = t; i < 96 * 64; i += 256) {
            int row = i >> 6, c = i & 63;
            float v;
            if (row < 64)      v = g_w[row * 64 + c];
            else if (row < 72) v = theta_w[(row - 64) * 64 + c] * LOG2E;
            else if (row < 80) v = phi_w[(row - 72) * 64 + c];
            else               v = 0.0f;
            Wbf[i] = (ushort_t)f2bf(v);
        }
        if (t < 96) {
            float bv = (t < 64) ? g_b[t]
                     : (t < 72) ? theta_b[t - 64] * LOG2E
                     : (t < 80) ? phi_b[t - 72] : 0.0f;
            biasf[t] = bv;
        }
    }
}

// ---------------- P2: projection GEMM: Y[96 x 128n] = W * X  per block ----------
__global__ __launch_bounds__(256) void p2_kernel(
    const ushort_t* __restrict__ xbf, const ushort_t* __restrict__ Wbf,
    const float* __restrict__ biasf,
    ushort_t* __restrict__ Qw, ushort_t* __restrict__ Kw, ushort_t* __restrict__ Vt)
{
    __shared__ ushort_t Xs[128 * XSTR];
    __shared__ float bs[96];

    const int t = threadIdx.x;
    const int lane = t & 63, w = t >> 6;
    const int l31 = lane & 31, hi = lane >> 5;
    const int b  = blockIdx.x >> 5;
    const int n0 = (blockIdx.x & 31) * 128;

    {
        const int n = t >> 1, h = t & 1;
        const ushort_t* src = xbf + ((size_t)(b * NN + n0 + n)) * 64 + h * 32;
        #pragma unroll
        for (int i = 0; i < 4; i++) {
            uint4 v = ((const uint4*)src)[i];
            *(uint4*)(Xs + n * XSTR + h * 32 + i * 8) = v;
        }
    }
    if (t < 96) bs[t] = biasf[t];
    __syncthreads();

    bf16x8 af[3][4];
    #pragma unroll
    for (int mt = 0; mt < 3; mt++)
        #pragma unroll
        for (int kc = 0; kc < 4; kc++)
            af[mt][kc] = *(const bf16x8*)(Wbf + (size_t)(mt * 32 + l31) * 64 + kc * 16 + hi * 8);

    f32x16 ac0 = {}, ac1 = {}, ac2 = {};
    #pragma unroll
    for (int kc = 0; kc < 4; kc++) {
        bf16x8 bv = *(const bf16x8*)(Xs + (w * 32 + l31) * XSTR + kc * 16 + hi * 8);
        ac0 = __builtin_amdgcn_mfma_f32_32x32x16_bf16(af[0][kc], bv, ac0, 0, 0, 0);
        ac1 = __builtin_amdgcn_mfma_f32_32x32x16_bf16(af[1][kc], bv, ac1, 0, 0, 0);
        ac2 = __builtin_amdgcn_mfma_f32_32x32x16_bf16(af[2][kc], bv, ac2, 0, 0, 0);
    }

    const int nw = n0 + w * 32;
    const int sig = ((l31 >> 3) & 1) * 16 + ((l31 >> 2) & 1) * 8 + ((l31 >> 4) & 1) * 4 + (l31 & 3);

    #pragma unroll
    for (int reg = 0; reg < 16; reg++) {
        int m = reg >> 2, r = reg & 3;
        {
            int ch = 4 * hi + 8 * m + r;
            float val = ac0[reg] + bs[ch];
            Vt[((size_t)(b * 64 + ch)) * NN + nw + sig] = (ushort_t)f2bf(val);
        }
        {
            int ch = 32 + 4 * hi + 8 * m + r;
            float val = ac1[reg] + bs[ch];
            Vt[((size_t)(b * 64 + ch)) * NN + nw + sig] = (ushort_t)f2bf(val);
        }
    }
    {
        float q0 = ac2[0] + bs[64 + 4 * hi + 0];
        float q1 = ac2[1] + bs[64 + 4 * hi + 1];
        float q2 = ac2[2] + bs[64 + 4 * hi + 2];
        float q3 = ac2[3] + bs[64 + 4 * hi + 3];
        uint2 qp = make_uint2(f2bf(q0) | (f2bf(q1) << 16), f2bf(q2) | (f2bf(q3) << 16));
        *(uint2*)(Qw + ((size_t)(b * NN) + nw + l31) * 8 + hi * 4) = qp;
        float p0 = ac2[4] + bs[72 + 4 * hi + 0];
        float p1 = ac2[5] + bs[72 + 4 * hi + 1];
        float p2 = ac2[6] + bs[72 + 4 * hi + 2];
        float p3 = ac2[7] + bs[72 + 4 * hi + 3];
        uint2 kp = make_uint2(f2bf(p0) | (f2bf(p1) << 16), f2bf(p2) | (f2bf(p3) << 16));
        *(uint2*)(Kw + ((size_t)(b * NN) + nw + l31) * 8 + hi * 4) = kp;
    }
}

// ---------------- attention: 32x32x16, m==0 softmax, register P, dbuf LDS ------
template <int FIN, int NSPLIT>
__global__ __launch_bounds__(256) void attn_kernel(
    const ushort_t* __restrict__ Qw, const ushort_t* __restrict__ Kw,
    const ushort_t* __restrict__ Vt,
    ushort_t* __restrict__ P, float* __restrict__ L,
    const float* __restrict__ x, const float* __restrict__ gamma,
    float* __restrict__ out)
{
    constexpr int KEYS = NN / NSPLIT;
    constexpr int NT = KEYS / 128;
    __shared__ ushort_t Vs[2][64][VSTR];   // 34816 B

    const int t = threadIdx.x;
    const int lane = t & 63, w = t >> 6;
    const int l31 = lane & 31, hi = lane >> 5;

    int bid = blockIdx.x;
    const int qt = bid & 31;
    const int b  = (bid >> 5) & 7;
    const int s  = bid >> 8;
    const int q0 = qt * 128 + w * 32;
    const int k0 = s * KEYS;

    const ushort_t* Kb = Kw + (size_t)b * NN * 8;
    const ushort_t* Vb = Vt + (size_t)b * 64 * NN;

    bf16x8 qf = {};
    if (hi == 0)
        qf = *(const bf16x8*)(Qw + ((size_t)b * NN + q0 + l31) * 8);

    const int vch = t >> 2, vsg = t & 3;
    const ushort_t* vsrc = Vb + (size_t)vch * NN + k0 + vsg * 32;

    uint4 vA[4];
    uint4 kcur[4] = {make_uint4(0,0,0,0), make_uint4(0,0,0,0),
                     make_uint4(0,0,0,0), make_uint4(0,0,0,0)};
    uint4 kA[4]   = {make_uint4(0,0,0,0), make_uint4(0,0,0,0),
                     make_uint4(0,0,0,0), make_uint4(0,0,0,0)};

    #pragma unroll
    for (int i = 0; i < 4; i++) vA[i] = *(const uint4*)(vsrc + i * 8);
    if (hi == 0) {
        #pragma unroll
        for (int kf = 0; kf < 4; kf++)
            kcur[kf] = *(const uint4*)(Kb + (size_t)(k0 + kf * 32 + l31) * 8);
    }
    #pragma unroll
    for (int i = 0; i < 4; i++)
        *(uint4*)(&Vs[0][vch][vsg * 32 + i * 8]) = vA[i];
    if (NT > 1) {
        #pragma unroll
        for (int i = 0; i < 4; i++) vA[i] = *(const uint4*)(vsrc + 128 + i * 8);
        if (hi == 0) {
            #pragma unroll
            for (int kf = 0; kf < 4; kf++)
                kA[kf] = *(const uint4*)(Kb + (size_t)(k0 + 128 + kf * 32 + l31) * 8);
        }
    }
    __syncthreads();

    f32x16 acc0 = {}, acc1 = {};
    float lsum = 0.0f;
    const f32x16 zf = {};

    for (int tt = 0; tt < NT; ++tt) {
        const int cur = tt & 1;
        // stage next tile into the other buffer (overlaps compute on cur)
        if (tt + 1 < NT) {
            #pragma unroll
            for (int i = 0; i < 4; i++)
                *(uint4*)(&Vs[cur ^ 1][vch][vsg * 32 + i * 8]) = vA[i];
        }
        // issue tile tt+2 global loads early
        if (tt + 2 < NT) {
            const ushort_t* v2 = vsrc + (size_t)(tt + 2) * 128;
            #pragma unroll
            for (int i = 0; i < 4; i++) vA[i] = *(const uint4*)(v2 + i * 8);
        }

        #pragma unroll
        for (int ks = 0; ks < 2; ks++) {
            U4B ka0, ka1;
            ka0.u = kcur[2 * ks];
            ka1.u = kcur[2 * ks + 1];
            f32x16 S0 = __builtin_amdgcn_mfma_f32_32x32x16_bf16(ka0.v, qf, zf, 0, 0, 0);
            f32x16 S1 = __builtin_amdgcn_mfma_f32_32x32x16_bf16(ka1.v, qf, zf, 0, 0, 0);

            float p0[16], p1[16];
            #pragma unroll
            for (int i = 0; i < 16; i++) p0[i] = fexp2(S0[i]);
            #pragma unroll
            for (int i = 0; i < 16; i++) p1[i] = fexp2(S1[i]);
            #pragma unroll
            for (int i = 0; i < 16; i++) { lsum += p0[i]; lsum += p1[i]; }

            uint_t pk0[8], pk1[8];
            #pragma unroll
            for (int m = 0; m < 4; m++) {
                #pragma unroll
                for (int rp = 0; rp < 2; rp++) {
                    pk0[m * 2 + rp] = packbf(p0[m * 4 + 2 * rp], p0[m * 4 + 2 * rp + 1]);
                    pk1[m * 2 + rp] = packbf(p1[m * 4 + 2 * rp], p1[m * 4 + 2 * rp + 1]);
                }
            }

            #pragma unroll
            for (int kf = 0; kf < 2; kf++) {
                #pragma unroll
                for (int c = 0; c < 2; c++) {
                    U4B bu;
                    if (kf == 0) bu.u = make_uint4(pk0[c * 2], pk0[c * 2 + 1],
                                                   pk0[(c + 2) * 2], pk0[(c + 2) * 2 + 1]);
                    else         bu.u = make_uint4(pk1[c * 2], pk1[c * 2 + 1],
                                                   pk1[(c + 2) * 2], pk1[(c + 2) * 2 + 1]);
                    bf16x8 av0 = *(const bf16x8*)(&Vs[cur][0 * 32 + l31][ks * 64 + kf * 32 + c * 16 + hi * 8]);
                    bf16x8 av1 = *(const bf16x8*)(&Vs[cur][1 * 32 + l31][ks * 64 + kf * 32 + c * 16 + hi * 8]);
                    acc0 = __builtin_amdgcn_mfma_f32_32x32x16_bf16(av0, bu.v, acc0, 0, 0, 0);
                    acc1 = __builtin_amdgcn_mfma_f32_32x32x16_bf16(av1, bu.v, acc1, 0, 0, 0);
                }
            }
        }

        if (tt + 1 < NT) {
            #pragma unroll
            for (int kf = 0; kf < 4; kf++) kcur[kf] = kA[kf];
        }
        if (tt + 2 < NT) {
            if (hi == 0) {
                const ushort_t* kk2 = Kb + (size_t)(k0 + (tt + 2) * 128) * 8;
                #pragma unroll
                for (int kf = 0; kf < 4; kf++)
                    kA[kf] = *(const uint4*)(kk2 + (size_t)(kf * 32 + l31) * 8);
            }
        }
        __syncthreads();
    }

    float ltot = lsum + __shfl_xor(lsum, 32);

    if (!FIN) {
        ushort_t* Pb = P + ((size_t)(s * Bb + b) * 64) * NN;
        #pragma unroll
        for (int reg = 0; reg < 16; reg++) {
            int m = reg >> 2, r = reg & 3;
            int ch0 = 4 * hi + 8 * m + r;
            Pb[(size_t)ch0 * NN + q0 + l31]        = (ushort_t)f2bf(acc0[reg]);
            Pb[(size_t)(ch0 + 32) * NN + q0 + l31] = (ushort_t)f2bf(acc1[reg]);
        }
        if (lane < 32)
            L[(size_t)(s * Bb + b) * NN + q0 + lane] = ltot;
    } else {
        const float gm = gamma[0];
        const float inv = 1.0f / ltot;
        #pragma unroll
        for (int reg = 0; reg < 16; reg++) {
            int m = reg >> 2, r = reg & 3;
            int ch0 = 4 * hi + 8 * m + r;
            size_t i0 = ((size_t)(b * 64 + ch0)) * NN + q0 + l31;
            size_t i1 = ((size_t)(b * 64 + ch0 + 32)) * NN + q0 + l31;
            out[i0] = x[i0] + gm * acc0[reg] * inv;
            out[i1] = x[i1] + gm * acc1[reg] * inv;
        }
    }
}

// ---------------- combine: thread = 8q x 8ch, vectorized ----------------------
__global__ __launch_bounds__(256) void combine_kernel(
    const ushort_t* __restrict__ P, const float* __restrict__ L,
    const float* __restrict__ x, const float* __restrict__ gamma,
    float* __restrict__ out, int nsplit)
{
    const int g = blockIdx.x * 256 + threadIdx.x;   // 32768 threads
    const int qo = g & 511;
    const int q0 = qo * 8;
    const int rest = g >> 9;                         // 0..63
    const int b  = rest & 7;
    const int cg = rest >> 3;                        // 0..7 -> ch0 = cg*8

    float ls[8];
    #pragma unroll
    for (int j = 0; j < 8; j++) ls[j] = 0.f;
    for (int s = 0; s < nsplit; s++) {
        const float* Lb = L + (size_t)(s * Bb + b) * NN + q0;
        float4 l0 = *(const float4*)(Lb);
        float4 l1 = *(const float4*)(Lb + 4);
        ls[0] += l0.x; ls[1] += l0.y; ls[2] += l0.z; ls[3] += l0.w;
        ls[4] += l1.x; ls[5] += l1.y; ls[6] += l1.z; ls[7] += l1.w;
    }

    float a[8][8];
    #pragma unroll
    for (int j = 0; j < 8; j++)
        #pragma unroll
        for (int k = 0; k < 8; k++) a[j][k] = 0.f;

    for (int s = 0; s < nsplit; s++) {
        #pragma unroll
        for (int j = 0; j < 8; j++) {
            const ushort_t* Pr = P + ((size_t)(s * Bb + b) * 64 + cg * 8 + j) * NN + q0;
            uint4 pv = *(const uint4*)Pr;
            uint_t u0 = pv.x, u1 = pv.y, u2 = pv.z, u3 = pv.w;
            a[j][0] += bitsf(u0 << 16); a[j][1] += bitsf(u0 & 0xFFFF0000u);
            a[j][2] += bitsf(u1 << 16); a[j][3] += bitsf(u1 & 0xFFFF0000u);
            a[j][4] += bitsf(u2 << 16); a[j][5] += bitsf(u2 & 0xFFFF0000u);
            a[j][6] += bitsf(u3 << 16); a[j][7] += bitsf(u3 & 0xFFFF0000u);
        }
    }

    float inv[8];
    #pragma unroll
    for (int k = 0; k < 8; k++) inv[k] = 1.0f / ls[k];
    const float gm = gamma[0];

    #pragma unroll
    for (int j = 0; j < 8; j++) {
        const size_t ro = ((size_t)(b * 64 + cg * 8 + j)) * NN + q0;
        float4 x0 = *(const float4*)(x + ro);
        float4 x1 = *(const float4*)(x + ro + 4);
        float4 o0, o1;
        o0.x = x0.x + gm * a[j][0] * inv[0];
        o0.y = x0.y + gm * a[j][1] * inv[1];
        o0.z = x0.z + gm * a[j][2] * inv[2];
        o0.w = x0.w + gm * a[j][3] * inv[3];
        o1.x = x1.x + gm * a[j][4] * inv[4];
        o1.y = x1.y + gm * a[j][5] * inv[5];
        o1.z = x1.z + gm * a[j][6] * inv[6];
        o1.w = x1.w + gm * a[j][7] * inv[7];
        *(float4*)(out + ro)     = o0;
        *(float4*)(out + ro + 4) = o1;
    }
}

extern "C" void kernel_launch(void* const* d_in, const int* in_sizes, int n_in,
                              void* d_out, int out_size, void* d_ws, size_t ws_size,
                              hipStream_t stream)
{
    const float* x       = (const float*)d_in[0];
    const float* theta_w = (const float*)d_in[1];
    const float* theta_b = (const float*)d_in[2];
    const float* phi_w   = (const float*)d_in[3];
    const float* phi_b   = (const float*)d_in[4];
    const float* g_w     = (const float*)d_in[5];
    const float* g_b     = (const float*)d_in[6];
    const float* gamma   = (const float*)d_in[7];
    float* out = (float*)d_out;

    // ws carve (all 16B aligned)
    char* p = (char*)d_ws;
    ushort_t* Qw  = (ushort_t*)p;  p += (size_t)Bb * NN * 8 * 2;        // 512 KB
    ushort_t* Kw  = (ushort_t*)p;  p += (size_t)Bb * NN * 8 * 2;        // 512 KB
    ushort_t* Vt  = (ushort_t*)p;  p += (size_t)Bb * 64 * NN * 2;       // 4 MB
    ushort_t* xbf = (ushort_t*)p;  p += (size_t)Bb * NN * 64 * 2;       // 4 MB
    ushort_t* Wbf = (ushort_t*)p;  p += 96 * 64 * 2;                    // 12 KB
    float*    biasf = (float*)p;   p += 96 * 4 + 128;                   // pad
    char*     pbase = p;
    const size_t base_bytes  = (size_t)(pbase - (char*)d_ws);
    const size_t split_bytes = (size_t)Bb * 64 * NN * 2 + (size_t)Bb * NN * 4;

    int ns = 1;
    const int cands[3] = {4, 2, 1};
    for (int i = 0; i < 3; i++)
        if (base_bytes + (size_t)cands[i] * split_bytes <= ws_size) { ns = cands[i]; break; }

    ushort_t* P = (ushort_t*)pbase;
    float*    L = (float*)(pbase + (size_t)ns * Bb * 64 * NN * 2);

    p1_kernel<<<513, 256, 0, stream>>>(x, theta_w, theta_b, phi_w, phi_b, g_w, g_b,
                                       xbf, Wbf, biasf);
    p2_kernel<<<Bb * 32, 256, 0, stream>>>(xbf, Wbf, biasf, Qw, Kw, Vt);

    if (ns == 4) {
        attn_kernel<0, 4><<<4 * Bb * 32, 256, 0, stream>>>(Qw, Kw, Vt, P, L,
                                                           x, gamma, out);
        combine_kernel<<<128, 256, 0, stream>>>(P, L, x, gamma, out, 4);
    } else if (ns == 2) {
        attn_kernel<0, 2><<<2 * Bb * 32, 256, 0, stream>>>(Qw, Kw, Vt, P, L,
                                                           x, gamma, out);
        combine_kernel<<<128, 256, 0, stream>>>(P, L, x, gamma, out, 2);
    } else {
        attn_kernel<1, 1><<<Bb * 32, 256, 0, stream>>>(Qw, Kw, Vt, P, L,
                                                       x, gamma, out);
    }
}

// Round 6
// 81.681 us; speedup vs baseline: 1.2975x; 1.2975x over previous
//
#include <hip/hip_runtime.h>
#include <cstddef>
#include <cstdint>

// SelfAttention2d: B=8, C=64, N=4096, IC=8
// R6: R4 attn structure (low VGPR) + bank-conflict-free swizzled Vs (VSTR=64,
// slot^=row&7) + ns up to 8 for occupancy. p1/p2 as before; R5 vectorized combine.

#define Bb 8
#define Cc 64
#define NN 4096
#define IC 8
#define XSTR 72      // LDS Xs row stride in P2

typedef __attribute__((ext_vector_type(8)))  short bf16x8;
typedef __attribute__((ext_vector_type(16))) float f32x16;
typedef unsigned short ushort_t;
typedef unsigned int   uint_t;

#define LOG2E 1.4426950408889634f
// swizzled LDS index (ushort elems): row*64 + (slot ^ (row&7))*8
#define VIDX(row, slot) (((row) << 6) + (((slot) ^ ((row) & 7)) << 3))

static __device__ __forceinline__ uint_t f2bf(float x) {   // RNE
    union { float f; uint_t u; } v; v.f = x;
    uint_t r = v.u + 0x7FFF + ((v.u >> 16) & 1);
    return r >> 16;
}
static __device__ __forceinline__ float bitsf(uint_t u) {
    union { uint_t u; float f; } v; v.u = u; return v.f;
}
static __device__ __forceinline__ float fexp2(float x) {
#if __has_builtin(__builtin_amdgcn_exp2f)
    return __builtin_amdgcn_exp2f(x);
#else
    return exp2f(x);
#endif
}
static __device__ __forceinline__ uint_t fbits(float x) {
    union { float f; uint_t u; } v; v.f = x; return v.u;
}
// pack (lo=even, hi=odd) truncated bf16 pair via v_perm
static __device__ __forceinline__ uint_t packbf(float e, float o) {
#if __has_builtin(__builtin_amdgcn_perm)
    return __builtin_amdgcn_perm(fbits(o), fbits(e), 0x07060302u);
#else
    return (fbits(e) >> 16) | (fbits(o) & 0xFFFF0000u);
#endif
}

union U4B { uint4 u; bf16x8 v; };

// ---------------- P1: transpose x -> xbf [b][n][c] bf16; block 512: weights ----
__global__ __launch_bounds__(256) void p1_kernel(
    const float* __restrict__ x,
    const float* __restrict__ theta_w, const float* __restrict__ theta_b,
    const float* __restrict__ phi_w,   const float* __restrict__ phi_b,
    const float* __restrict__ g_w,     const float* __restrict__ g_b,
    ushort_t* __restrict__ xbf, ushort_t* __restrict__ Wbf, float* __restrict__ biasf)
{
    const int t = threadIdx.x;
    const int bid = blockIdx.x;
    if (bid < 512) {
        __shared__ float Xt[64 * 68];
        const int b  = bid >> 6;
        const int nt = (bid & 63) * 64;
        const int c = t >> 2, nsg = t & 3;
        const float* xs = x + ((size_t)(b * 64 + c)) * NN + nt + nsg * 16;
        #pragma unroll
        for (int i = 0; i < 4; i++) {
            float4 v = ((const float4*)xs)[i];
            *(float4*)(Xt + c * 68 + nsg * 16 + i * 4) = v;
        }
        __syncthreads();
        const int n = t & 63, cs = t >> 6;
        uint_t wv[8];
        #pragma unroll
        for (int i = 0; i < 8; i++) {
            float e0 = Xt[(cs * 16 + 2 * i + 0) * 68 + n];
            float e1 = Xt[(cs * 16 + 2 * i + 1) * 68 + n];
            wv[i] = f2bf(e0) | (f2bf(e1) << 16);
        }
        ushort_t* dst = xbf + ((size_t)(b * NN + nt + n)) * 64 + cs * 16;
        *(uint4*)dst       = make_uint4(wv[0], wv[1], wv[2], wv[3]);
        *(uint4*)(dst + 8) = make_uint4(wv[4], wv[5], wv[6], wv[7]);
    } else {
        // weights: Wbf[96][64] = [g(0-63); theta*log2e(64-71); phi(72-79); zero]
        for (int i = t; i < 96 * 64; i += 256) {
            int row = i >> 6, c = i & 63;
            float v;
            if (row < 64)      v = g_w[row * 64 + c];
            else if (row < 72) v = theta_w[(row - 64) * 64 + c] * LOG2E;
            else if (row < 80) v = phi_w[(row - 72) * 64 + c];
            else               v = 0.0f;
            Wbf[i] = (ushort_t)f2bf(v);
        }
        if (t < 96) {
            float bv = (t < 64) ? g_b[t]
                     : (t < 72) ? theta_b[t - 64] * LOG2E
                     : (t < 80) ? phi_b[t - 72] : 0.0f;
            biasf[t] = bv;
        }
    }
}

// ---------------- P2: projection GEMM: Y[96 x 128n] = W * X  per block ----------
__global__ __launch_bounds__(256) void p2_kernel(
    const ushort_t* __restrict__ xbf, const ushort_t* __restrict__ Wbf,
    const float* __restrict__ biasf,
    ushort_t* __restrict__ Qw, ushort_t* __restrict__ Kw, ushort_t* __restrict__ Vt)
{
    __shared__ ushort_t Xs[128 * XSTR];
    __shared__ float bs[96];

    const int t = threadIdx.x;
    const int lane = t & 63, w = t >> 6;
    const int l31 = lane & 31, hi = lane >> 5;
    const int b  = blockIdx.x >> 5;
    const int n0 = (blockIdx.x & 31) * 128;

    {
        const int n = t >> 1, h = t & 1;
        const ushort_t* src = xbf + ((size_t)(b * NN + n0 + n)) * 64 + h * 32;
        #pragma unroll
        for (int i = 0; i < 4; i++) {
            uint4 v = ((const uint4*)src)[i];
            *(uint4*)(Xs + n * XSTR + h * 32 + i * 8) = v;
        }
    }
    if (t < 96) bs[t] = biasf[t];
    __syncthreads();

    bf16x8 af[3][4];
    #pragma unroll
    for (int mt = 0; mt < 3; mt++)
        #pragma unroll
        for (int kc = 0; kc < 4; kc++)
            af[mt][kc] = *(const bf16x8*)(Wbf + (size_t)(mt * 32 + l31) * 64 + kc * 16 + hi * 8);

    f32x16 ac0 = {}, ac1 = {}, ac2 = {};
    #pragma unroll
    for (int kc = 0; kc < 4; kc++) {
        bf16x8 bv = *(const bf16x8*)(Xs + (w * 32 + l31) * XSTR + kc * 16 + hi * 8);
        ac0 = __builtin_amdgcn_mfma_f32_32x32x16_bf16(af[0][kc], bv, ac0, 0, 0, 0);
        ac1 = __builtin_amdgcn_mfma_f32_32x32x16_bf16(af[1][kc], bv, ac1, 0, 0, 0);
        ac2 = __builtin_amdgcn_mfma_f32_32x32x16_bf16(af[2][kc], bv, ac2, 0, 0, 0);
    }

    const int nw = n0 + w * 32;
    const int sig = ((l31 >> 3) & 1) * 16 + ((l31 >> 2) & 1) * 8 + ((l31 >> 4) & 1) * 4 + (l31 & 3);

    #pragma unroll
    for (int reg = 0; reg < 16; reg++) {
        int m = reg >> 2, r = reg & 3;
        {
            int ch = 4 * hi + 8 * m + r;
            float val = ac0[reg] + bs[ch];
            Vt[((size_t)(b * 64 + ch)) * NN + nw + sig] = (ushort_t)f2bf(val);
        }
        {
            int ch = 32 + 4 * hi + 8 * m + r;
            float val = ac1[reg] + bs[ch];
            Vt[((size_t)(b * 64 + ch)) * NN + nw + sig] = (ushort_t)f2bf(val);
        }
    }
    {
        float q0 = ac2[0] + bs[64 + 4 * hi + 0];
        float q1 = ac2[1] + bs[64 + 4 * hi + 1];
        float q2 = ac2[2] + bs[64 + 4 * hi + 2];
        float q3 = ac2[3] + bs[64 + 4 * hi + 3];
        uint2 qp = make_uint2(f2bf(q0) | (f2bf(q1) << 16), f2bf(q2) | (f2bf(q3) << 16));
        *(uint2*)(Qw + ((size_t)(b * NN) + nw + l31) * 8 + hi * 4) = qp;
        float p0 = ac2[4] + bs[72 + 4 * hi + 0];
        float p1 = ac2[5] + bs[72 + 4 * hi + 1];
        float p2 = ac2[6] + bs[72 + 4 * hi + 2];
        float p3 = ac2[7] + bs[72 + 4 * hi + 3];
        uint2 kp = make_uint2(f2bf(p0) | (f2bf(p1) << 16), f2bf(p2) | (f2bf(p3) << 16));
        *(uint2*)(Kw + ((size_t)(b * NN) + nw + l31) * 8 + hi * 4) = kp;
    }
}

// ---------------- attention: 32x32x16, m==0 softmax, register P ----------------
// R4 structure; Vs is slot-swizzled [64][64] (bank-conflict-free).
template <int FIN>
__global__ __launch_bounds__(256) void attn_kernel(
    const ushort_t* __restrict__ Qw, const ushort_t* __restrict__ Kw,
    const ushort_t* __restrict__ Vt,
    ushort_t* __restrict__ P, float* __restrict__ L, int nsplit,
    const float* __restrict__ x, const float* __restrict__ gamma,
    float* __restrict__ out)
{
    __shared__ ushort_t Vs[64 * 64];     // 8 KB, swizzled

    const int t = threadIdx.x;
    const int lane = t & 63, w = t >> 6;
    const int l31 = lane & 31, hi = lane >> 5;

    int bid = blockIdx.x;
    const int qt = bid & 31;
    const int b  = (bid >> 5) & 7;
    const int s  = bid >> 8;
    const int q0 = qt * 128 + w * 32;
    const int keys = NN / nsplit;
    const int k0 = s * keys;
    const int ntiles = keys / 64;

    const ushort_t* Kb = Kw + (size_t)b * NN * 8;
    const ushort_t* Vb = Vt + (size_t)b * 64 * NN;

    bf16x8 qf = {};
    if (hi == 0)
        qf = *(const bf16x8*)(Qw + ((size_t)b * NN + q0 + l31) * 8);

    const int vch = t >> 2, vsg = t & 3;
    const ushort_t* vsrc = Vb + (size_t)vch * NN + k0 + vsg * 16;
    const int ws0 = VIDX(vch, 2 * vsg);
    const int ws1 = VIDX(vch, 2 * vsg + 1);

    uint4 vc0 = *(const uint4*)(vsrc);
    uint4 vc1 = *(const uint4*)(vsrc + 8);
    uint4 kc0 = {}, kc1 = {};
    if (hi == 0) {
        kc0 = *(const uint4*)(Kb + (size_t)(k0 + l31) * 8);
        kc1 = *(const uint4*)(Kb + (size_t)(k0 + 32 + l31) * 8);
    }

    f32x16 acc0 = {}, acc1 = {};
    float lsum = 0.0f;
    const f32x16 zf = {};

    for (int tt = 0; tt < ntiles; ++tt) {
        __syncthreads();
        *(uint4*)(Vs + ws0) = vc0;
        *(uint4*)(Vs + ws1) = vc1;
        __syncthreads();

        uint4 vn0 = {}, vn1 = {}, kn0 = {}, kn1 = {};
        if (tt + 1 < ntiles) {
            const ushort_t* vs2 = vsrc + (size_t)(tt + 1) * 64;
            vn0 = *(const uint4*)(vs2);
            vn1 = *(const uint4*)(vs2 + 8);
            if (hi == 0) {
                kn0 = *(const uint4*)(Kb + (size_t)(k0 + (tt + 1) * 64 + l31) * 8);
                kn1 = *(const uint4*)(Kb + (size_t)(k0 + (tt + 1) * 64 + 32 + l31) * 8);
            }
        }

        // QK^T (swapped): S^T[k][q], lane: q=l31, k = kf*32 + 4*hi + 8*m + r
        U4B ka0, ka1; ka0.u = kc0; ka1.u = kc1;
        f32x16 S0 = __builtin_amdgcn_mfma_f32_32x32x16_bf16(ka0.v, qf, zf, 0, 0, 0);
        f32x16 S1 = __builtin_amdgcn_mfma_f32_32x32x16_bf16(ka1.v, qf, zf, 0, 0, 0);

        float p0[16], p1[16];
        #pragma unroll
        for (int i = 0; i < 16; i++) { p0[i] = fexp2(S0[i]); }
        #pragma unroll
        for (int i = 0; i < 16; i++) { p1[i] = fexp2(S1[i]); }
        #pragma unroll
        for (int i = 0; i < 16; i++) { lsum += p0[i]; lsum += p1[i]; }

        uint_t pk0[8], pk1[8];
        #pragma unroll
        for (int m = 0; m < 4; m++) {
            #pragma unroll
            for (int rp = 0; rp < 2; rp++) {
                pk0[m * 2 + rp] = packbf(p0[m * 4 + 2 * rp], p0[m * 4 + 2 * rp + 1]);
                pk1[m * 2 + rp] = packbf(p1[m * 4 + 2 * rp], p1[m * 4 + 2 * rp + 1]);
            }
        }

        // PV: acc[ch][q] += V-frag * P-frag (slot-matched via sigma permutation)
        #pragma unroll
        for (int kf = 0; kf < 2; kf++) {
            #pragma unroll
            for (int c = 0; c < 2; c++) {
                U4B bu;
                if (kf == 0) bu.u = make_uint4(pk0[c * 2], pk0[c * 2 + 1], pk0[(c + 2) * 2], pk0[(c + 2) * 2 + 1]);
                else         bu.u = make_uint4(pk1[c * 2], pk1[c * 2 + 1], pk1[(c + 2) * 2], pk1[(c + 2) * 2 + 1]);
                const int slot = kf * 4 + c * 2 + hi;
                bf16x8 av0 = *(const bf16x8*)(Vs + VIDX(l31, slot));
                bf16x8 av1 = *(const bf16x8*)(Vs + VIDX(32 + l31, slot));
                acc0 = __builtin_amdgcn_mfma_f32_32x32x16_bf16(av0, bu.v, acc0, 0, 0, 0);
                acc1 = __builtin_amdgcn_mfma_f32_32x32x16_bf16(av1, bu.v, acc1, 0, 0, 0);
            }
        }

        vc0 = vn0; vc1 = vn1; kc0 = kn0; kc1 = kn1;
    }

    float ltot = lsum + __shfl_xor(lsum, 32);

    if (!FIN) {
        ushort_t* Pb = P + ((size_t)(s * Bb + b) * 64) * NN;
        #pragma unroll
        for (int reg = 0; reg < 16; reg++) {
            int m = reg >> 2, r = reg & 3;
            int ch0 = 4 * hi + 8 * m + r;
            Pb[(size_t)ch0 * NN + q0 + l31]        = (ushort_t)f2bf(acc0[reg]);
            Pb[(size_t)(ch0 + 32) * NN + q0 + l31] = (ushort_t)f2bf(acc1[reg]);
        }
        if (lane < 32)
            L[(size_t)(s * Bb + b) * NN + q0 + lane] = ltot;
    } else {
        const float gm = gamma[0];
        const float inv = 1.0f / ltot;
        #pragma unroll
        for (int reg = 0; reg < 16; reg++) {
            int m = reg >> 2, r = reg & 3;
            int ch0 = 4 * hi + 8 * m + r;
            size_t i0 = ((size_t)(b * 64 + ch0)) * NN + q0 + l31;
            size_t i1 = ((size_t)(b * 64 + ch0 + 32)) * NN + q0 + l31;
            out[i0] = x[i0] + gm * acc0[reg] * inv;
            out[i1] = x[i1] + gm * acc1[reg] * inv;
        }
    }
}

// ---------------- combine: thread = 8q x 8ch, vectorized ----------------------
__global__ __launch_bounds__(256) void combine_kernel(
    const ushort_t* __restrict__ P, const float* __restrict__ L,
    const float* __restrict__ x, const float* __restrict__ gamma,
    float* __restrict__ out, int nsplit)
{
    const int g = blockIdx.x * 256 + threadIdx.x;   // 32768 threads
    const int qo = g & 511;
    const int q0 = qo * 8;
    const int rest = g >> 9;                         // 0..63
    const int b  = rest & 7;
    const int cg = rest >> 3;                        // 0..7 -> ch0 = cg*8

    float ls[8];
    #pragma unroll
    for (int j = 0; j < 8; j++) ls[j] = 0.f;
    for (int s = 0; s < nsplit; s++) {
        const float* Lb = L + (size_t)(s * Bb + b) * NN + q0;
        float4 l0 = *(const float4*)(Lb);
        float4 l1 = *(const float4*)(Lb + 4);
        ls[0] += l0.x; ls[1] += l0.y; ls[2] += l0.z; ls[3] += l0.w;
        ls[4] += l1.x; ls[5] += l1.y; ls[6] += l1.z; ls[7] += l1.w;
    }

    float a[8][8];
    #pragma unroll
    for (int j = 0; j < 8; j++)
        #pragma unroll
        for (int k = 0; k < 8; k++) a[j][k] = 0.f;

    for (int s = 0; s < nsplit; s++) {
        #pragma unroll
        for (int j = 0; j < 8; j++) {
            const ushort_t* Pr = P + ((size_t)(s * Bb + b) * 64 + cg * 8 + j) * NN + q0;
            uint4 pv = *(const uint4*)Pr;
            uint_t u0 = pv.x, u1 = pv.y, u2 = pv.z, u3 = pv.w;
            a[j][0] += bitsf(u0 << 16); a[j][1] += bitsf(u0 & 0xFFFF0000u);
            a[j][2] += bitsf(u1 << 16); a[j][3] += bitsf(u1 & 0xFFFF0000u);
            a[j][4] += bitsf(u2 << 16); a[j][5] += bitsf(u2 & 0xFFFF0000u);
            a[j][6] += bitsf(u3 << 16); a[j][7] += bitsf(u3 & 0xFFFF0000u);
        }
    }

    float inv[8];
    #pragma unroll
    for (int k = 0; k < 8; k++) inv[k] = 1.0f / ls[k];
    const float gm = gamma[0];

    #pragma unroll
    for (int j = 0; j < 8; j++) {
        const size_t ro = ((size_t)(b * 64 + cg * 8 + j)) * NN + q0;
        float4 x0 = *(const float4*)(x + ro);
        float4 x1 = *(const float4*)(x + ro + 4);
        float4 o0, o1;
        o0.x = x0.x + gm * a[j][0] * inv[0];
        o0.y = x0.y + gm * a[j][1] * inv[1];
        o0.z = x0.z + gm * a[j][2] * inv[2];
        o0.w = x0.w + gm * a[j][3] * inv[3];
        o1.x = x1.x + gm * a[j][4] * inv[4];
        o1.y = x1.y + gm * a[j][5] * inv[5];
        o1.z = x1.z + gm * a[j][6] * inv[6];
        o1.w = x1.w + gm * a[j][7] * inv[7];
        *(float4*)(out + ro)     = o0;
        *(float4*)(out + ro + 4) = o1;
    }
}

extern "C" void kernel_launch(void* const* d_in, const int* in_sizes, int n_in,
                              void* d_out, int out_size, void* d_ws, size_t ws_size,
                              hipStream_t stream)
{
    const float* x       = (const float*)d_in[0];
    const float* theta_w = (const float*)d_in[1];
    const float* theta_b = (const float*)d_in[2];
    const float* phi_w   = (const float*)d_in[3];
    const float* phi_b   = (const float*)d_in[4];
    const float* g_w     = (const float*)d_in[5];
    const float* g_b     = (const float*)d_in[6];
    const float* gamma   = (const float*)d_in[7];
    float* out = (float*)d_out;

    // ws carve (all 16B aligned)
    char* p = (char*)d_ws;
    ushort_t* Qw  = (ushort_t*)p;  p += (size_t)Bb * NN * 8 * 2;        // 512 KB
    ushort_t* Kw  = (ushort_t*)p;  p += (size_t)Bb * NN * 8 * 2;        // 512 KB
    ushort_t* Vt  = (ushort_t*)p;  p += (size_t)Bb * 64 * NN * 2;       // 4 MB
    ushort_t* xbf = (ushort_t*)p;  p += (size_t)Bb * NN * 64 * 2;       // 4 MB
    ushort_t* Wbf = (ushort_t*)p;  p += 96 * 64 * 2;                    // 12 KB
    float*    biasf = (float*)p;   p += 96 * 4 + 128;                   // pad
    char*     pbase = p;
    const size_t base_bytes  = (size_t)(pbase - (char*)d_ws);
    const size_t split_bytes = (size_t)Bb * 64 * NN * 2 + (size_t)Bb * NN * 4;

    int ns = 1;
    const int cands[4] = {8, 4, 2, 1};
    for (int i = 0; i < 4; i++)
        if (base_bytes + (size_t)cands[i] * split_bytes <= ws_size) { ns = cands[i]; break; }

    ushort_t* P = (ushort_t*)pbase;
    float*    L = (float*)(pbase + (size_t)ns * Bb * 64 * NN * 2);

    p1_kernel<<<513, 256, 0, stream>>>(x, theta_w, theta_b, phi_w, phi_b, g_w, g_b,
                                       xbf, Wbf, biasf);
    p2_kernel<<<Bb * 32, 256, 0, stream>>>(xbf, Wbf, biasf, Qw, Kw, Vt);

    if (ns > 1) {
        attn_kernel<0><<<ns * Bb * 32, 256, 0, stream>>>(Qw, Kw, Vt, P, L, ns,
                                                         nullptr, nullptr, nullptr);
        combine_kernel<<<128, 256, 0, stream>>>(P, L, x, gamma, out, ns);
    } else {
        attn_kernel<1><<<Bb * 32, 256, 0, stream>>>(Qw, Kw, Vt, P, L, 1,
                                                    x, gamma, out);
    }
}

// Round 7
// 66.804 us; speedup vs baseline: 1.5865x; 1.2227x over previous
//
#include <hip/hip_runtime.h>
#include <cstddef>
#include <cstdint>

// SelfAttention2d: B=8, C=64, N=4096, IC=8
// R7: R6 with ns capped at 4 (P-partial traffic beat occupancy at ns=8).
// Swizzled bank-balanced Vs, low-VGPR attn, vectorized combine on 256 blocks.

#define Bb 8
#define Cc 64
#define NN 4096
#define IC 8
#define XSTR 72      // LDS Xs row stride in P2

typedef __attribute__((ext_vector_type(8)))  short bf16x8;
typedef __attribute__((ext_vector_type(16))) float f32x16;
typedef unsigned short ushort_t;
typedef unsigned int   uint_t;

#define LOG2E 1.4426950408889634f
// swizzled LDS index (ushort elems): row*64 + (slot ^ (row&7))*8
#define VIDX(row, slot) (((row) << 6) + (((slot) ^ ((row) & 7)) << 3))

static __device__ __forceinline__ uint_t f2bf(float x) {   // RNE
    union { float f; uint_t u; } v; v.f = x;
    uint_t r = v.u + 0x7FFF + ((v.u >> 16) & 1);
    return r >> 16;
}
static __device__ __forceinline__ float bitsf(uint_t u) {
    union { uint_t u; float f; } v; v.u = u; return v.f;
}
static __device__ __forceinline__ float fexp2(float x) {
#if __has_builtin(__builtin_amdgcn_exp2f)
    return __builtin_amdgcn_exp2f(x);
#else
    return exp2f(x);
#endif
}
static __device__ __forceinline__ uint_t fbits(float x) {
    union { float f; uint_t u; } v; v.f = x; return v.u;
}
// pack (lo=even, hi=odd) truncated bf16 pair via v_perm
static __device__ __forceinline__ uint_t packbf(float e, float o) {
#if __has_builtin(__builtin_amdgcn_perm)
    return __builtin_amdgcn_perm(fbits(o), fbits(e), 0x07060302u);
#else
    return (fbits(e) >> 16) | (fbits(o) & 0xFFFF0000u);
#endif
}

union U4B { uint4 u; bf16x8 v; };

// ---------------- P1: transpose x -> xbf [b][n][c] bf16; block 512: weights ----
__global__ __launch_bounds__(256) void p1_kernel(
    const float* __restrict__ x,
    const float* __restrict__ theta_w, const float* __restrict__ theta_b,
    const float* __restrict__ phi_w,   const float* __restrict__ phi_b,
    const float* __restrict__ g_w,     const float* __restrict__ g_b,
    ushort_t* __restrict__ xbf, ushort_t* __restrict__ Wbf, float* __restrict__ biasf)
{
    const int t = threadIdx.x;
    const int bid = blockIdx.x;
    if (bid < 512) {
        __shared__ float Xt[64 * 68];
        const int b  = bid >> 6;
        const int nt = (bid & 63) * 64;
        const int c = t >> 2, nsg = t & 3;
        const float* xs = x + ((size_t)(b * 64 + c)) * NN + nt + nsg * 16;
        #pragma unroll
        for (int i = 0; i < 4; i++) {
            float4 v = ((const float4*)xs)[i];
            *(float4*)(Xt + c * 68 + nsg * 16 + i * 4) = v;
        }
        __syncthreads();
        const int n = t & 63, cs = t >> 6;
        uint_t wv[8];
        #pragma unroll
        for (int i = 0; i < 8; i++) {
            float e0 = Xt[(cs * 16 + 2 * i + 0) * 68 + n];
            float e1 = Xt[(cs * 16 + 2 * i + 1) * 68 + n];
            wv[i] = f2bf(e0) | (f2bf(e1) << 16);
        }
        ushort_t* dst = xbf + ((size_t)(b * NN + nt + n)) * 64 + cs * 16;
        *(uint4*)dst       = make_uint4(wv[0], wv[1], wv[2], wv[3]);
        *(uint4*)(dst + 8) = make_uint4(wv[4], wv[5], wv[6], wv[7]);
    } else {
        // weights: Wbf[96][64] = [g(0-63); theta*log2e(64-71); phi(72-79); zero]
        for (int i = t; i < 96 * 64; i += 256) {
            int row = i >> 6, c = i & 63;
            float v;
            if (row < 64)      v = g_w[row * 64 + c];
            else if (row < 72) v = theta_w[(row - 64) * 64 + c] * LOG2E;
            else if (row < 80) v = phi_w[(row - 72) * 64 + c];
            else               v = 0.0f;
            Wbf[i] = (ushort_t)f2bf(v);
        }
        if (t < 96) {
            float bv = (t < 64) ? g_b[t]
                     : (t < 72) ? theta_b[t - 64] * LOG2E
                     : (t < 80) ? phi_b[t - 72] : 0.0f;
            biasf[t] = bv;
        }
    }
}

// ---------------- P2: projection GEMM: Y[96 x 128n] = W * X  per block ----------
__global__ __launch_bounds__(256) void p2_kernel(
    const ushort_t* __restrict__ xbf, const ushort_t* __restrict__ Wbf,
    const float* __restrict__ biasf,
    ushort_t* __restrict__ Qw, ushort_t* __restrict__ Kw, ushort_t* __restrict__ Vt)
{
    __shared__ ushort_t Xs[128 * XSTR];
    __shared__ float bs[96];

    const int t = threadIdx.x;
    const int lane = t & 63, w = t >> 6;
    const int l31 = lane & 31, hi = lane >> 5;
    const int b  = blockIdx.x >> 5;
    const int n0 = (blockIdx.x & 31) * 128;

    {
        const int n = t >> 1, h = t & 1;
        const ushort_t* src = xbf + ((size_t)(b * NN + n0 + n)) * 64 + h * 32;
        #pragma unroll
        for (int i = 0; i < 4; i++) {
            uint4 v = ((const uint4*)src)[i];
            *(uint4*)(Xs + n * XSTR + h * 32 + i * 8) = v;
        }
    }
    if (t < 96) bs[t] = biasf[t];
    __syncthreads();

    bf16x8 af[3][4];
    #pragma unroll
    for (int mt = 0; mt < 3; mt++)
        #pragma unroll
        for (int kc = 0; kc < 4; kc++)
            af[mt][kc] = *(const bf16x8*)(Wbf + (size_t)(mt * 32 + l31) * 64 + kc * 16 + hi * 8);

    f32x16 ac0 = {}, ac1 = {}, ac2 = {};
    #pragma unroll
    for (int kc = 0; kc < 4; kc++) {
        bf16x8 bv = *(const bf16x8*)(Xs + (w * 32 + l31) * XSTR + kc * 16 + hi * 8);
        ac0 = __builtin_amdgcn_mfma_f32_32x32x16_bf16(af[0][kc], bv, ac0, 0, 0, 0);
        ac1 = __builtin_amdgcn_mfma_f32_32x32x16_bf16(af[1][kc], bv, ac1, 0, 0, 0);
        ac2 = __builtin_amdgcn_mfma_f32_32x32x16_bf16(af[2][kc], bv, ac2, 0, 0, 0);
    }

    const int nw = n0 + w * 32;
    const int sig = ((l31 >> 3) & 1) * 16 + ((l31 >> 2) & 1) * 8 + ((l31 >> 4) & 1) * 4 + (l31 & 3);

    #pragma unroll
    for (int reg = 0; reg < 16; reg++) {
        int m = reg >> 2, r = reg & 3;
        {
            int ch = 4 * hi + 8 * m + r;
            float val = ac0[reg] + bs[ch];
            Vt[((size_t)(b * 64 + ch)) * NN + nw + sig] = (ushort_t)f2bf(val);
        }
        {
            int ch = 32 + 4 * hi + 8 * m + r;
            float val = ac1[reg] + bs[ch];
            Vt[((size_t)(b * 64 + ch)) * NN + nw + sig] = (ushort_t)f2bf(val);
        }
    }
    {
        float q0 = ac2[0] + bs[64 + 4 * hi + 0];
        float q1 = ac2[1] + bs[64 + 4 * hi + 1];
        float q2 = ac2[2] + bs[64 + 4 * hi + 2];
        float q3 = ac2[3] + bs[64 + 4 * hi + 3];
        uint2 qp = make_uint2(f2bf(q0) | (f2bf(q1) << 16), f2bf(q2) | (f2bf(q3) << 16));
        *(uint2*)(Qw + ((size_t)(b * NN) + nw + l31) * 8 + hi * 4) = qp;
        float p0 = ac2[4] + bs[72 + 4 * hi + 0];
        float p1 = ac2[5] + bs[72 + 4 * hi + 1];
        float p2 = ac2[6] + bs[72 + 4 * hi + 2];
        float p3 = ac2[7] + bs[72 + 4 * hi + 3];
        uint2 kp = make_uint2(f2bf(p0) | (f2bf(p1) << 16), f2bf(p2) | (f2bf(p3) << 16));
        *(uint2*)(Kw + ((size_t)(b * NN) + nw + l31) * 8 + hi * 4) = kp;
    }
}

// ---------------- attention: 32x32x16, m==0 softmax, register P ----------------
// Low-VGPR structure; Vs is slot-swizzled [64][64] (bank-balanced).
template <int FIN>
__global__ __launch_bounds__(256) void attn_kernel(
    const ushort_t* __restrict__ Qw, const ushort_t* __restrict__ Kw,
    const ushort_t* __restrict__ Vt,
    ushort_t* __restrict__ P, float* __restrict__ L, int nsplit,
    const float* __restrict__ x, const float* __restrict__ gamma,
    float* __restrict__ out)
{
    __shared__ ushort_t Vs[64 * 64];     // 8 KB, swizzled

    const int t = threadIdx.x;
    const int lane = t & 63, w = t >> 6;
    const int l31 = lane & 31, hi = lane >> 5;

    int bid = blockIdx.x;
    const int qt = bid & 31;
    const int b  = (bid >> 5) & 7;
    const int s  = bid >> 8;
    const int q0 = qt * 128 + w * 32;
    const int keys = NN / nsplit;
    const int k0 = s * keys;
    const int ntiles = keys / 64;

    const ushort_t* Kb = Kw + (size_t)b * NN * 8;
    const ushort_t* Vb = Vt + (size_t)b * 64 * NN;

    bf16x8 qf = {};
    if (hi == 0)
        qf = *(const bf16x8*)(Qw + ((size_t)b * NN + q0 + l31) * 8);

    const int vch = t >> 2, vsg = t & 3;
    const ushort_t* vsrc = Vb + (size_t)vch * NN + k0 + vsg * 16;
    const int ws0 = VIDX(vch, 2 * vsg);
    const int ws1 = VIDX(vch, 2 * vsg + 1);

    uint4 vc0 = *(const uint4*)(vsrc);
    uint4 vc1 = *(const uint4*)(vsrc + 8);
    uint4 kc0 = {}, kc1 = {};
    if (hi == 0) {
        kc0 = *(const uint4*)(Kb + (size_t)(k0 + l31) * 8);
        kc1 = *(const uint4*)(Kb + (size_t)(k0 + 32 + l31) * 8);
    }

    f32x16 acc0 = {}, acc1 = {};
    float lsum = 0.0f;
    const f32x16 zf = {};

    for (int tt = 0; tt < ntiles; ++tt) {
        __syncthreads();
        *(uint4*)(Vs + ws0) = vc0;
        *(uint4*)(Vs + ws1) = vc1;
        __syncthreads();

        uint4 vn0 = {}, vn1 = {}, kn0 = {}, kn1 = {};
        if (tt + 1 < ntiles) {
            const ushort_t* vs2 = vsrc + (size_t)(tt + 1) * 64;
            vn0 = *(const uint4*)(vs2);
            vn1 = *(const uint4*)(vs2 + 8);
            if (hi == 0) {
                kn0 = *(const uint4*)(Kb + (size_t)(k0 + (tt + 1) * 64 + l31) * 8);
                kn1 = *(const uint4*)(Kb + (size_t)(k0 + (tt + 1) * 64 + 32 + l31) * 8);
            }
        }

        // QK^T (swapped): S^T[k][q], lane: q=l31, k = kf*32 + 4*hi + 8*m + r
        U4B ka0, ka1; ka0.u = kc0; ka1.u = kc1;
        f32x16 S0 = __builtin_amdgcn_mfma_f32_32x32x16_bf16(ka0.v, qf, zf, 0, 0, 0);
        f32x16 S1 = __builtin_amdgcn_mfma_f32_32x32x16_bf16(ka1.v, qf, zf, 0, 0, 0);

        float p0[16], p1[16];
        #pragma unroll
        for (int i = 0; i < 16; i++) { p0[i] = fexp2(S0[i]); }
        #pragma unroll
        for (int i = 0; i < 16; i++) { p1[i] = fexp2(S1[i]); }
        #pragma unroll
        for (int i = 0; i < 16; i++) { lsum += p0[i]; lsum += p1[i]; }

        uint_t pk0[8], pk1[8];
        #pragma unroll
        for (int m = 0; m < 4; m++) {
            #pragma unroll
            for (int rp = 0; rp < 2; rp++) {
                pk0[m * 2 + rp] = packbf(p0[m * 4 + 2 * rp], p0[m * 4 + 2 * rp + 1]);
                pk1[m * 2 + rp] = packbf(p1[m * 4 + 2 * rp], p1[m * 4 + 2 * rp + 1]);
            }
        }

        // PV: acc[ch][q] += V-frag * P-frag (slot-matched via sigma permutation)
        #pragma unroll
        for (int kf = 0; kf < 2; kf++) {
            #pragma unroll
            for (int c = 0; c < 2; c++) {
                U4B bu;
                if (kf == 0) bu.u = make_uint4(pk0[c * 2], pk0[c * 2 + 1], pk0[(c + 2) * 2], pk0[(c + 2) * 2 + 1]);
                else         bu.u = make_uint4(pk1[c * 2], pk1[c * 2 + 1], pk1[(c + 2) * 2], pk1[(c + 2) * 2 + 1]);
                const int slot = kf * 4 + c * 2 + hi;
                bf16x8 av0 = *(const bf16x8*)(Vs + VIDX(l31, slot));
                bf16x8 av1 = *(const bf16x8*)(Vs + VIDX(32 + l31, slot));
                acc0 = __builtin_amdgcn_mfma_f32_32x32x16_bf16(av0, bu.v, acc0, 0, 0, 0);
                acc1 = __builtin_amdgcn_mfma_f32_32x32x16_bf16(av1, bu.v, acc1, 0, 0, 0);
            }
        }

        vc0 = vn0; vc1 = vn1; kc0 = kn0; kc1 = kn1;
    }

    float ltot = lsum + __shfl_xor(lsum, 32);

    if (!FIN) {
        ushort_t* Pb = P + ((size_t)(s * Bb + b) * 64) * NN;
        #pragma unroll
        for (int reg = 0; reg < 16; reg++) {
            int m = reg >> 2, r = reg & 3;
            int ch0 = 4 * hi + 8 * m + r;
            Pb[(size_t)ch0 * NN + q0 + l31]        = (ushort_t)f2bf(acc0[reg]);
            Pb[(size_t)(ch0 + 32) * NN + q0 + l31] = (ushort_t)f2bf(acc1[reg]);
        }
        if (lane < 32)
            L[(size_t)(s * Bb + b) * NN + q0 + lane] = ltot;
    } else {
        const float gm = gamma[0];
        const float inv = 1.0f / ltot;
        #pragma unroll
        for (int reg = 0; reg < 16; reg++) {
            int m = reg >> 2, r = reg & 3;
            int ch0 = 4 * hi + 8 * m + r;
            size_t i0 = ((size_t)(b * 64 + ch0)) * NN + q0 + l31;
            size_t i1 = ((size_t)(b * 64 + ch0 + 32)) * NN + q0 + l31;
            out[i0] = x[i0] + gm * acc0[reg] * inv;
            out[i1] = x[i1] + gm * acc1[reg] * inv;
        }
    }
}

// ---------------- combine: thread = 8q x 8ch, vectorized, 256 blocks ----------
__global__ __launch_bounds__(128) void combine_kernel(
    const ushort_t* __restrict__ P, const float* __restrict__ L,
    const float* __restrict__ x, const float* __restrict__ gamma,
    float* __restrict__ out, int nsplit)
{
    const int g = blockIdx.x * 128 + threadIdx.x;   // 32768 threads
    const int qo = g & 511;
    const int q0 = qo * 8;
    const int rest = g >> 9;                         // 0..63
    const int b  = rest & 7;
    const int cg = rest >> 3;                        // 0..7 -> ch0 = cg*8

    float ls[8];
    #pragma unroll
    for (int j = 0; j < 8; j++) ls[j] = 0.f;
    for (int s = 0; s < nsplit; s++) {
        const float* Lb = L + (size_t)(s * Bb + b) * NN + q0;
        float4 l0 = *(const float4*)(Lb);
        float4 l1 = *(const float4*)(Lb + 4);
        ls[0] += l0.x; ls[1] += l0.y; ls[2] += l0.z; ls[3] += l0.w;
        ls[4] += l1.x; ls[5] += l1.y; ls[6] += l1.z; ls[7] += l1.w;
    }

    float a[8][8];
    #pragma unroll
    for (int j = 0; j < 8; j++)
        #pragma unroll
        for (int k = 0; k < 8; k++) a[j][k] = 0.f;

    for (int s = 0; s < nsplit; s++) {
        #pragma unroll
        for (int j = 0; j < 8; j++) {
            const ushort_t* Pr = P + ((size_t)(s * Bb + b) * 64 + cg * 8 + j) * NN + q0;
            uint4 pv = *(const uint4*)Pr;
            uint_t u0 = pv.x, u1 = pv.y, u2 = pv.z, u3 = pv.w;
            a[j][0] += bitsf(u0 << 16); a[j][1] += bitsf(u0 & 0xFFFF0000u);
            a[j][2] += bitsf(u1 << 16); a[j][3] += bitsf(u1 & 0xFFFF0000u);
            a[j][4] += bitsf(u2 << 16); a[j][5] += bitsf(u2 & 0xFFFF0000u);
            a[j][6] += bitsf(u3 << 16); a[j][7] += bitsf(u3 & 0xFFFF0000u);
        }
    }

    float inv[8];
    #pragma unroll
    for (int k = 0; k < 8; k++) inv[k] = 1.0f / ls[k];
    const float gm = gamma[0];

    #pragma unroll
    for (int j = 0; j < 8; j++) {
        const size_t ro = ((size_t)(b * 64 + cg * 8 + j)) * NN + q0;
        float4 x0 = *(const float4*)(x + ro);
        float4 x1 = *(const float4*)(x + ro + 4);
        float4 o0, o1;
        o0.x = x0.x + gm * a[j][0] * inv[0];
        o0.y = x0.y + gm * a[j][1] * inv[1];
        o0.z = x0.z + gm * a[j][2] * inv[2];
        o0.w = x0.w + gm * a[j][3] * inv[3];
        o1.x = x1.x + gm * a[j][4] * inv[4];
        o1.y = x1.y + gm * a[j][5] * inv[5];
        o1.z = x1.z + gm * a[j][6] * inv[6];
        o1.w = x1.w + gm * a[j][7] * inv[7];
        *(float4*)(out + ro)     = o0;
        *(float4*)(out + ro + 4) = o1;
    }
}

extern "C" void kernel_launch(void* const* d_in, const int* in_sizes, int n_in,
                              void* d_out, int out_size, void* d_ws, size_t ws_size,
                              hipStream_t stream)
{
    const float* x       = (const float*)d_in[0];
    const float* theta_w = (const float*)d_in[1];
    const float* theta_b = (const float*)d_in[2];
    const float* phi_w   = (const float*)d_in[3];
    const float* phi_b   = (const float*)d_in[4];
    const float* g_w     = (const float*)d_in[5];
    const float* g_b     = (const float*)d_in[6];
    const float* gamma   = (const float*)d_in[7];
    float* out = (float*)d_out;

    // ws carve (all 16B aligned)
    char* p = (char*)d_ws;
    ushort_t* Qw  = (ushort_t*)p;  p += (size_t)Bb * NN * 8 * 2;        // 512 KB
    ushort_t* Kw  = (ushort_t*)p;  p += (size_t)Bb * NN * 8 * 2;        // 512 KB
    ushort_t* Vt  = (ushort_t*)p;  p += (size_t)Bb * 64 * NN * 2;       // 4 MB
    ushort_t* xbf = (ushort_t*)p;  p += (size_t)Bb * NN * 64 * 2;       // 4 MB
    ushort_t* Wbf = (ushort_t*)p;  p += 96 * 64 * 2;                    // 12 KB
    float*    biasf = (float*)p;   p += 96 * 4 + 128;                   // pad
    char*     pbase = p;
    const size_t base_bytes  = (size_t)(pbase - (char*)d_ws);
    const size_t split_bytes = (size_t)Bb * 64 * NN * 2 + (size_t)Bb * NN * 4;

    int ns = 1;
    const int cands[3] = {4, 2, 1};
    for (int i = 0; i < 3; i++)
        if (base_bytes + (size_t)cands[i] * split_bytes <= ws_size) { ns = cands[i]; break; }

    ushort_t* P = (ushort_t*)pbase;
    float*    L = (float*)(pbase + (size_t)ns * Bb * 64 * NN * 2);

    p1_kernel<<<513, 256, 0, stream>>>(x, theta_w, theta_b, phi_w, phi_b, g_w, g_b,
                                       xbf, Wbf, biasf);
    p2_kernel<<<Bb * 32, 256, 0, stream>>>(xbf, Wbf, biasf, Qw, Kw, Vt);

    if (ns > 1) {
        attn_kernel<0><<<ns * Bb * 32, 256, 0, stream>>>(Qw, Kw, Vt, P, L, ns,
                                                         nullptr, nullptr, nullptr);
        combine_kernel<<<256, 128, 0, stream>>>(P, L, x, gamma, out, ns);
    } else {
        attn_kernel<1><<<Bb * 32, 256, 0, stream>>>(Qw, Kw, Vt, P, L, 1,
                                                    x, gamma, out);
    }
}